// Round 3
// baseline (353.995 us; speedup 1.0000x reference)
//
#include <hip/hip_runtime.h>
#include <math.h>

// MoE router: X[8192,4096] fp32 @ Wt[4096,64] -> logits[8192,64] -> top2 -> softmax -> scatter.
// d_out = probs[8192*64] ++ routing_map[8192*64] (floats).
// ws: Wt (1MB) | part [8][8192][64] (16MB)
//
// R1: lane=token raw X reads -> 4x overfetch. Fixed by LDS staging (R2).
// R2: VALUBusy 30% -- per-j s_waitcnt lgkmcnt(0) on the 64-SGPR W row (no SGPR
//     room to double-buffer W) + single-buffered staging. Fix (R3): 2 tokens
//     per lane (256 FMA cycles per W-row stall) + double-buffered x staging.

#define HDIM 4096
#define NEXP 64
#define NTOK 8192
#define HG 8                 // h-groups across blocks
#define HSLAB (HDIM / HG)    // 512 h per block
#define NCHUNK (HSLAB / 64)  // 8 staged chunks of 64 h
#define TPB 128              // tokens per block (two per lane)
#define XSTRIDE 65           // LDS row stride: odd -> 2-way bank access (free)

// ---------------- kernel 0: transpose W[64][4096] -> Wt[4096][64] ----------------
__global__ void wtrans_kernel(const float* __restrict__ W, float* __restrict__ Wt) {
    __shared__ float tile[64][65];
    int h0 = blockIdx.x * 64;
    int lx = threadIdx.x & 63;
    int ly = threadIdx.x >> 6;               // 0..3
    #pragma unroll
    for (int p = 0; p < 16; ++p) {
        int e = p * 4 + ly;
        tile[lx][e] = W[(size_t)e * HDIM + h0 + lx];   // coalesced over lx
    }
    __syncthreads();
    #pragma unroll
    for (int p = 0; p < 16; ++p) {
        int hh = p * 4 + ly;
        Wt[(size_t)(h0 + hh) * NEXP + lx] = tile[hh][lx];  // coalesced over lx
    }
}

// ---------------- kernel 1: partial logits ----------------
__global__ __launch_bounds__(256, 2) void logits_kernel(
        const float* __restrict__ X, const float* __restrict__ Wt,
        float* __restrict__ part) {
    const int tg   = blockIdx.x >> 3;        // token group 0..63 (128 tokens each)
    const int hg   = blockIdx.x & 7;         // h group 0..7
    const int lane = threadIdx.x & 63;
    const int wave = __builtin_amdgcn_readfirstlane((int)(threadIdx.x >> 6)); // 0..3

    // arena: xs[2][128][XSTRIDE] (66.6KB) overlaid later by red[4][128][17] (34.8KB)
    __shared__ float smem[2 * TPB * XSTRIDE];
    float* xs0 = smem;
    float* xs1 = smem + TPB * XSTRIDE;
    float (*red)[TPB][17] = reinterpret_cast<float(*)[TPB][17]>(smem);

    const int token0 = tg * TPB;
    const int hbase  = hg * HSLAB;

    float acc0[NEXP], acc1[NEXP];
    #pragma unroll
    for (int e = 0; e < NEXP; ++e) { acc0[e] = 0.f; acc1[e] = 0.f; }

    const float* Xblk = X + (size_t)token0 * HDIM + hbase;
    const int r4 = threadIdx.x >> 4;         // 0..15 (row group)
    const int f4 = threadIdx.x & 15;         // float4 slot within 64-h row

    // stage chunk 0
    float4 pf[8];
    #pragma unroll
    for (int q = 0; q < 8; ++q) {
        int r = q * 16 + r4;
        pf[q] = *reinterpret_cast<const float4*>(Xblk + (size_t)r * HDIM + f4 * 4);
    }
    #pragma unroll
    for (int q = 0; q < 8; ++q) {
        int r = q * 16 + r4;
        float* dst = xs0 + r * XSTRIDE + f4 * 4;   // scalar writes keep stride-65 rows
        dst[0] = pf[q].x; dst[1] = pf[q].y; dst[2] = pf[q].z; dst[3] = pf[q].w;
    }
    __syncthreads();

    const int xoff = lane * XSTRIDE + wave * 16;   // this wave's j-window base

    for (int c = 0; c < NCHUNK; ++c) {
        float* cur = (c & 1) ? xs1 : xs0;
        float* nxt = (c & 1) ? xs0 : xs1;
        if (c + 1 < NCHUNK) {                      // prefetch chunk c+1 (issues now)
            #pragma unroll
            for (int q = 0; q < 8; ++q) {
                int r = q * 16 + r4;
                pf[q] = *reinterpret_cast<const float4*>(
                    Xblk + (size_t)r * HDIM + (c + 1) * 64 + f4 * 4);
            }
        }
        // wave w covers h-local [w*16, w*16+16); W row wave-uniform -> s_load bcast
        const float* wrow = Wt + (size_t)(hbase + c * 64 + wave * 16) * NEXP;
        #pragma unroll
        for (int j = 0; j < 16; ++j) {
            float x0 = cur[xoff + j];                       // 2-way bank: free
            float x1 = cur[xoff + 64 * XSTRIDE + j];
            const float* w = wrow + (size_t)j * NEXP;
            #pragma unroll
            for (int e = 0; e < NEXP; ++e) {
                acc0[e] = fmaf(x0, w[e], acc0[e]);          // 256 FMA cycles per
                acc1[e] = fmaf(x1, w[e], acc1[e]);          // one W-row lgkm wait
            }
        }
        if (c + 1 < NCHUNK) {
            #pragma unroll
            for (int q = 0; q < 8; ++q) {
                int r = q * 16 + r4;
                float* dst = nxt + r * XSTRIDE + f4 * 4;
                dst[0] = pf[q].x; dst[1] = pf[q].y; dst[2] = pf[q].z; dst[3] = pf[q].w;
            }
        }
        __syncthreads();
    }

    // cross-wave reduce, 4 expert-chunks of 16 (arena overlays xs)
    const int ec = threadIdx.x & 15;
    const int tq = threadIdx.x >> 4;         // 0..15
    #pragma unroll
    for (int ce = 0; ce < 4; ++ce) {
        __syncthreads();
        #pragma unroll
        for (int i = 0; i < 16; ++i) {
            red[wave][lane][i]      = acc0[ce * 16 + i];
            red[wave][lane + 64][i] = acc1[ce * 16 + i];
        }
        __syncthreads();
        #pragma unroll
        for (int p = 0; p < 8; ++p) {
            int t = p * 16 + tq;
            float s = red[0][t][ec] + red[1][t][ec] + red[2][t][ec] + red[3][t][ec];
            part[((size_t)hg * NTOK + token0 + t) * NEXP + ce * 16 + ec] = s;
        }
    }
}

// ---------------- kernel 2: reduce HG partials, top-2 softmax, scatter ----------------
__global__ __launch_bounds__(256) void topk_kernel(
        const float* __restrict__ part, float* __restrict__ probs,
        float* __restrict__ rmap) {
    const int wave = threadIdx.x >> 6;
    const int lane = threadIdx.x & 63;       // lane = expert
    const int token = blockIdx.x * 4 + wave;

    const float* p = part + (size_t)token * NEXP + lane;
    float v = 0.f;
    #pragma unroll
    for (int hg = 0; hg < HG; ++hg) v += p[(size_t)hg * NTOK * NEXP];

    // top-1 (lower index wins ties, like lax.top_k)
    float m1 = v; int i1 = lane;
    #pragma unroll
    for (int s = 32; s > 0; s >>= 1) {
        float om = __shfl_xor(m1, s, 64);
        int   oi = __shfl_xor(i1, s, 64);
        if (om > m1 || (om == m1 && oi < i1)) { m1 = om; i1 = oi; }
    }
    // top-2: exclude i1
    float vx = (lane == i1) ? -INFINITY : v;
    float m2 = vx; int i2 = lane;
    #pragma unroll
    for (int s = 32; s > 0; s >>= 1) {
        float om = __shfl_xor(m2, s, 64);
        int   oi = __shfl_xor(i2, s, 64);
        if (om > m2 || (om == m2 && oi < i2)) { m2 = om; i2 = oi; }
    }

    float e2 = expf(m2 - m1);
    float p1 = 1.f / (1.f + e2);
    float p2 = 1.f - p1;

    float prob = (lane == i1) ? p1 : ((lane == i2) ? p2 : 0.f);
    float flag = (lane == i1 || lane == i2) ? 1.f : 0.f;
    probs[(size_t)token * NEXP + lane] = prob;
    rmap [(size_t)token * NEXP + lane] = flag;
}

extern "C" void kernel_launch(void* const* d_in, const int* in_sizes, int n_in,
                              void* d_out, int out_size, void* d_ws, size_t ws_size,
                              hipStream_t stream) {
    const float* X = (const float*)d_in[0];   // [8192,4096]
    const float* W = (const float*)d_in[1];   // [64,4096]
    float* out   = (float*)d_out;
    float* Wt    = (float*)d_ws;                       // 262144 floats
    float* part  = Wt + (size_t)HDIM * NEXP;           // 8*8192*64 floats

    wtrans_kernel<<<HDIM / 64, 256, 0, stream>>>(W, Wt);
    logits_kernel<<<64 * HG, 256, 0, stream>>>(X, Wt, part);
    topk_kernel<<<NTOK / 4, 256, 0, stream>>>(part, out, out + (size_t)NTOK * NEXP);
}

// Round 4
// 273.222 us; speedup vs baseline: 1.2956x; 1.2956x over previous
//
#include <hip/hip_runtime.h>
#include <math.h>

// MoE router: X[8192,4096] fp32 @ Wt[4096,64] -> logits[8192,64] -> top2 -> softmax -> scatter.
// d_out = probs[8192*64] ++ routing_map[8192*64] (floats).
// ws: Wt (1MB) | part [8][8192][64] (16MB)
//
// R1: lane=token raw X reads -> 4x overfetch (517MB). Fixed via LDS staging.
// R2: 96us, VALUBusy 30% but VALU-busy TIME == 27.3us FMA floor -> issue is
//     unoverlapped stalls: per-j s_waitcnt lgkmcnt(0) on SMEM W row (SMEM is
//     out-of-order -> full drain) stalls waves in lockstep.
// R3 FAILED: 2 tokens/lane needed ~170 live VGPRs -> AGPR/scratch traffic,
//     VALU time 3x floor. Lesson: acc must stay <= 64/lane.
// R4: W also staged in LDS; inner loop reads W rows via ds_read_b128
//     BROADCAST (same addr all lanes, conflict-free). DS is in-order ->
//     compiler emits fine-grained lgkmcnt(N) (m97 pattern), no full drains.

#define HDIM 4096
#define NEXP 64
#define NTOK 8192
#define HG 8                 // h-groups across blocks
#define HSLAB (HDIM / HG)    // 512 h per block
#define NCHUNK (HSLAB / 64)  // 8 staged chunks of 64 h
#define TPB 64               // tokens per block (one per lane)
#define XSTRIDE 65           // x rows: odd stride -> 2-way bank access (free)

// ---------------- kernel 0: transpose W[64][4096] -> Wt[4096][64] ----------------
__global__ void wtrans_kernel(const float* __restrict__ W, float* __restrict__ Wt) {
    __shared__ float tile[64][65];
    int h0 = blockIdx.x * 64;
    int lx = threadIdx.x & 63;
    int ly = threadIdx.x >> 6;               // 0..3
    #pragma unroll
    for (int p = 0; p < 16; ++p) {
        int e = p * 4 + ly;
        tile[lx][e] = W[(size_t)e * HDIM + h0 + lx];   // coalesced over lx
    }
    __syncthreads();
    #pragma unroll
    for (int p = 0; p < 16; ++p) {
        int hh = p * 4 + ly;
        Wt[(size_t)(h0 + hh) * NEXP + lx] = tile[hh][lx];  // coalesced over lx
    }
}

// ---------------- kernel 1: partial logits ----------------
__global__ __launch_bounds__(256) void logits_kernel(
        const float* __restrict__ X, const float* __restrict__ Wt,
        float* __restrict__ part) {
    const int tg   = blockIdx.x >> 3;        // token group 0..127
    const int hg   = blockIdx.x & 7;         // h group 0..7
    const int lane = threadIdx.x & 63;
    const int wave = __builtin_amdgcn_readfirstlane((int)(threadIdx.x >> 6)); // 0..3

    // arena (33 KB): xs[64][65] (16640B) | wt_s[64][64] (16384B, 16B-aligned
    // since 16640%16==0 -> ds_read_b128-able). Overlaid at the end by
    // red[4][64][17] (17408B).
    __shared__ float smem[64 * XSTRIDE + 64 * NEXP];
    float (*xs)[XSTRIDE] = reinterpret_cast<float(*)[XSTRIDE]>(smem);
    float* wt_s          = smem + 64 * XSTRIDE;
    float (*red)[TPB][17] = reinterpret_cast<float(*)[TPB][17]>(smem);

    const int token0 = tg * TPB;
    const int hbase  = hg * HSLAB;

    float acc[NEXP];
    #pragma unroll
    for (int e = 0; e < NEXP; ++e) acc[e] = 0.f;

    const float* Xblk = X + (size_t)token0 * HDIM + hbase;
    const int r4 = threadIdx.x >> 4;         // 0..15
    const int f4 = threadIdx.x & 15;         // float4 slot within a 64-float row

    for (int c = 0; c < NCHUNK; ++c) {
        __syncthreads();                     // arena safe to overwrite
        // stage x tile: 64 tokens x 64 h, coalesced (16 lanes = 256B contig)
        #pragma unroll
        for (int q = 0; q < 4; ++q) {
            int r = q * 16 + r4;
            float4 v = *reinterpret_cast<const float4*>(
                Xblk + (size_t)r * HDIM + c * 64 + f4 * 4);
            float* dst = &xs[r][f4 * 4];     // stride-65 rows: scalar stores
            dst[0] = v.x; dst[1] = v.y; dst[2] = v.z; dst[3] = v.w;
        }
        // stage W chunk: 64 h x 64 e, coalesced; float4 stores (16B aligned)
        #pragma unroll
        for (int q = 0; q < 4; ++q) {
            int row = q * 16 + r4;
            float4 v = *reinterpret_cast<const float4*>(
                Wt + (size_t)(hbase + c * 64 + row) * NEXP + f4 * 4);
            *reinterpret_cast<float4*>(wt_s + row * NEXP + f4 * 4) = v;
        }
        __syncthreads();
        // wave w covers h-local [w*16, w*16+16)
        #pragma unroll
        for (int j = 0; j < 16; ++j) {
            float xv = xs[lane][wave * 16 + j];               // 2-way: free
            const float4* wr = reinterpret_cast<const float4*>(
                wt_s + (wave * 16 + j) * NEXP);               // broadcast rows
            #pragma unroll
            for (int q = 0; q < 16; ++q) {
                float4 w = wr[q];                             // ds_read_b128 bcast
                acc[q * 4 + 0] = fmaf(xv, w.x, acc[q * 4 + 0]);
                acc[q * 4 + 1] = fmaf(xv, w.y, acc[q * 4 + 1]);
                acc[q * 4 + 2] = fmaf(xv, w.z, acc[q * 4 + 2]);
                acc[q * 4 + 3] = fmaf(xv, w.w, acc[q * 4 + 3]);
            }
        }
    }

    // cross-wave reduce, 4 expert-chunks of 16 (arena overlays xs/wt_s)
    const int ec = threadIdx.x & 15;
    const int tq = threadIdx.x >> 4;         // 0..15
    #pragma unroll
    for (int ce = 0; ce < 4; ++ce) {
        __syncthreads();
        #pragma unroll
        for (int i = 0; i < 16; ++i) red[wave][lane][i] = acc[ce * 16 + i];
        __syncthreads();
        #pragma unroll
        for (int p = 0; p < 4; ++p) {
            int t = p * 16 + tq;
            float s = red[0][t][ec] + red[1][t][ec] + red[2][t][ec] + red[3][t][ec];
            part[((size_t)hg * NTOK + token0 + t) * NEXP + ce * 16 + ec] = s;
        }
    }
}

// ---------------- kernel 2: reduce HG partials, top-2 softmax, scatter ----------------
__global__ __launch_bounds__(256) void topk_kernel(
        const float* __restrict__ part, float* __restrict__ probs,
        float* __restrict__ rmap) {
    const int wave = threadIdx.x >> 6;
    const int lane = threadIdx.x & 63;       // lane = expert
    const int token = blockIdx.x * 4 + wave;

    const float* p = part + (size_t)token * NEXP + lane;
    float v = 0.f;
    #pragma unroll
    for (int hg = 0; hg < HG; ++hg) v += p[(size_t)hg * NTOK * NEXP];

    // top-1 (lower index wins ties, like lax.top_k)
    float m1 = v; int i1 = lane;
    #pragma unroll
    for (int s = 32; s > 0; s >>= 1) {
        float om = __shfl_xor(m1, s, 64);
        int   oi = __shfl_xor(i1, s, 64);
        if (om > m1 || (om == m1 && oi < i1)) { m1 = om; i1 = oi; }
    }
    // top-2: exclude i1
    float vx = (lane == i1) ? -INFINITY : v;
    float m2 = vx; int i2 = lane;
    #pragma unroll
    for (int s = 32; s > 0; s >>= 1) {
        float om = __shfl_xor(m2, s, 64);
        int   oi = __shfl_xor(i2, s, 64);
        if (om > m2 || (om == m2 && oi < i2)) { m2 = om; i2 = oi; }
    }

    float e2 = expf(m2 - m1);
    float p1 = 1.f / (1.f + e2);
    float p2 = 1.f - p1;

    float prob = (lane == i1) ? p1 : ((lane == i2) ? p2 : 0.f);
    float flag = (lane == i1 || lane == i2) ? 1.f : 0.f;
    probs[(size_t)token * NEXP + lane] = prob;
    rmap [(size_t)token * NEXP + lane] = flag;
}

extern "C" void kernel_launch(void* const* d_in, const int* in_sizes, int n_in,
                              void* d_out, int out_size, void* d_ws, size_t ws_size,
                              hipStream_t stream) {
    const float* X = (const float*)d_in[0];   // [8192,4096]
    const float* W = (const float*)d_in[1];   // [64,4096]
    float* out   = (float*)d_out;
    float* Wt    = (float*)d_ws;                       // 262144 floats
    float* part  = Wt + (size_t)HDIM * NEXP;           // 8*8192*64 floats

    wtrans_kernel<<<HDIM / 64, 256, 0, stream>>>(W, Wt);
    logits_kernel<<<128 * HG, 256, 0, stream>>>(X, Wt, part);
    topk_kernel<<<NTOK / 4, 256, 0, stream>>>(part, out, out + (size_t)NTOK * NEXP);
}

// Round 5
// 220.873 us; speedup vs baseline: 1.6027x; 1.2370x over previous
//
#include <hip/hip_runtime.h>
#include <math.h>

// MoE router: X[8192,4096] fp32 @ W^T -> logits[8192,64] -> top2 softmax scatter.
// d_out = probs[8192*64] ++ routing_map[8192*64] (floats).
// ws: part [8][8192][64] fp32 (16MB)
//
// R1: lane=token raw X reads -> 4x overfetch. Fixed via LDS staging.
// R2: 96us. VALU-busy TIME == 27.3us FMA floor; duty 30% -- per-j SMEM W row
//     needs lgkmcnt(0) full drain (SMEM retires OOO; prefetch unfixable).
// R3 FAILED: 2 tokens/lane -> ~170 live VGPRs -> scratch/AGPR traffic. acc<=64.
// R4 FAILED: W via per-j ds_read_b128 broadcast -> 16 b128/j/wave floods the
//     per-CU LDS pipe (~6x oversubscribed vs VALU). Duty 22%.
// R5: 8x8 register-tile outer product: 64 FMAs per 4 ds_read_b128 per k.
//     1 wave/block (no barrier coupling), k-major LDS tiles (stride 68),
//     global->reg prefetch of next chunk under compute. LDS pipe <= ~50%.

#define HDIM 4096
#define NEXP 64
#define NTOK 8192
#define HG 8
#define HSLAB (HDIM / HG)   // 512 k per block
#define KK 16               // k per staged chunk
#define NCH (HSLAB / KK)    // 32 chunks
#define TPBK 64             // tokens per block (wave)
#define XS 68               // LDS row stride (floats): rows 16B-aligned, ~2-way banks

// ---------------- kernel 1: partial logits ----------------
__global__ __launch_bounds__(64, 1) void logits_kernel(
        const float* __restrict__ X, const float* __restrict__ W,
        float* __restrict__ part) {
    const int tg   = blockIdx.x >> 3;   // 0..127
    const int hg   = blockIdx.x & 7;    // 0..7
    const int lane = threadIdx.x;       // 0..63
    const int tr   = lane >> 3;         // token-row group 0..7
    const int ec   = lane & 7;          // expert-col group 0..7

    __shared__ __align__(16) float smem[2 * KK * XS];   // 8704 B
    float* xs = smem;                   // [KK][XS]: xs[k][token]
    float* ws = smem + KK * XS;         // [KK][XS]: ws[k][expert]

    const int token0 = tg * TPBK;
    const int hbase  = hg * HSLAB;

    const int r4 = lane >> 2;           // 0..15
    const int sl = lane & 3;            // 0..3

    float acc[8][8];
    #pragma unroll
    for (int i = 0; i < 8; ++i)
        #pragma unroll
        for (int j = 0; j < 8; ++j) acc[i][j] = 0.f;

    const float* Xb = X + (size_t)token0 * HDIM + hbase;

    float4 pfx[4], pfw[4];
    // ---- prologue: load + store chunk 0 ----
    #pragma unroll
    for (int p = 0; p < 4; ++p) {       // x tile 64t x 16k, coalesced 4 lanes/row
        int row = p * 16 + r4;
        pfx[p] = *reinterpret_cast<const float4*>(Xb + (size_t)row * HDIM + sl * 4);
    }
    #pragma unroll
    for (int q = 0; q < 4; ++q) {       // w tile 64e x 16k, coalesced 4 lanes/row
        int idx = q * 64 + lane;
        int e = idx >> 2, s2 = idx & 3;
        pfw[q] = *reinterpret_cast<const float4*>(W + (size_t)e * HDIM + hbase + s2 * 4);
    }
    #pragma unroll
    for (int p = 0; p < 4; ++p) {       // transpose-scatter to k-major (~2-way banks)
        int row = p * 16 + r4;
        xs[(sl * 4 + 0) * XS + row] = pfx[p].x;
        xs[(sl * 4 + 1) * XS + row] = pfx[p].y;
        xs[(sl * 4 + 2) * XS + row] = pfx[p].z;
        xs[(sl * 4 + 3) * XS + row] = pfx[p].w;
    }
    #pragma unroll
    for (int q = 0; q < 4; ++q) {
        int idx = q * 64 + lane;
        int e = idx >> 2, s2 = idx & 3;
        ws[(s2 * 4 + 0) * XS + e] = pfw[q].x;
        ws[(s2 * 4 + 1) * XS + e] = pfw[q].y;
        ws[(s2 * 4 + 2) * XS + e] = pfw[q].z;
        ws[(s2 * 4 + 3) * XS + e] = pfw[q].w;
    }
    __syncthreads();                    // single wave: trivial, just orders LDS

    for (int c = 0; c < NCH; ++c) {
        if (c + 1 < NCH) {              // global prefetch of next chunk (hidden)
            const int off = (c + 1) * KK;
            #pragma unroll
            for (int p = 0; p < 4; ++p) {
                int row = p * 16 + r4;
                pfx[p] = *reinterpret_cast<const float4*>(
                    Xb + (size_t)row * HDIM + off + sl * 4);
            }
            #pragma unroll
            for (int q = 0; q < 4; ++q) {
                int idx = q * 64 + lane;
                int e = idx >> 2, s2 = idx & 3;
                pfw[q] = *reinterpret_cast<const float4*>(
                    W + (size_t)e * HDIM + hbase + off + s2 * 4);
            }
        }
        // ---- compute: per k, 4 ds_read_b128 -> 64 FMAs ----
        #pragma unroll
        for (int k = 0; k < KK; ++k) {
            const float4* xr = reinterpret_cast<const float4*>(xs + k * XS + tr * 8);
            const float4* wr = reinterpret_cast<const float4*>(ws + k * XS + ec * 8);
            float4 xa = xr[0], xb = xr[1];     // 8-way broadcast groups, 2-way banks
            float4 wa = wr[0], wb = wr[1];
            float xv[8] = {xa.x, xa.y, xa.z, xa.w, xb.x, xb.y, xb.z, xb.w};
            float wv[8] = {wa.x, wa.y, wa.z, wa.w, wb.x, wb.y, wb.z, wb.w};
            #pragma unroll
            for (int i = 0; i < 8; ++i)
                #pragma unroll
                for (int j = 0; j < 8; ++j)
                    acc[i][j] = fmaf(xv[i], wv[j], acc[i][j]);
        }
        __syncthreads();
        if (c + 1 < NCH) {              // commit prefetched chunk to LDS
            #pragma unroll
            for (int p = 0; p < 4; ++p) {
                int row = p * 16 + r4;
                xs[(sl * 4 + 0) * XS + row] = pfx[p].x;
                xs[(sl * 4 + 1) * XS + row] = pfx[p].y;
                xs[(sl * 4 + 2) * XS + row] = pfx[p].z;
                xs[(sl * 4 + 3) * XS + row] = pfx[p].w;
            }
            #pragma unroll
            for (int q = 0; q < 4; ++q) {
                int idx = q * 64 + lane;
                int e = idx >> 2, s2 = idx & 3;
                ws[(s2 * 4 + 0) * XS + e] = pfw[q].x;
                ws[(s2 * 4 + 1) * XS + e] = pfw[q].y;
                ws[(s2 * 4 + 2) * XS + e] = pfw[q].z;
                ws[(s2 * 4 + 3) * XS + e] = pfw[q].w;
            }
        }
        __syncthreads();
    }

    // ---- epilogue: per lane 8 tokens x 8 consecutive experts, float4 stores ----
    float* dst = part + ((size_t)hg * NTOK + token0) * NEXP;
    #pragma unroll
    for (int i = 0; i < 8; ++i) {
        int t = tr * 8 + i;
        *reinterpret_cast<float4*>(dst + (size_t)t * NEXP + ec * 8) =
            make_float4(acc[i][0], acc[i][1], acc[i][2], acc[i][3]);
        *reinterpret_cast<float4*>(dst + (size_t)t * NEXP + ec * 8 + 4) =
            make_float4(acc[i][4], acc[i][5], acc[i][6], acc[i][7]);
    }
}

// ---------------- kernel 2: reduce HG partials, top-2 softmax, scatter ----------------
__global__ __launch_bounds__(256) void topk_kernel(
        const float* __restrict__ part, float* __restrict__ probs,
        float* __restrict__ rmap) {
    const int wave = threadIdx.x >> 6;
    const int lane = threadIdx.x & 63;       // lane = expert
    const int token = blockIdx.x * 4 + wave;

    const float* p = part + (size_t)token * NEXP + lane;
    float v = 0.f;
    #pragma unroll
    for (int hg = 0; hg < HG; ++hg) v += p[(size_t)hg * NTOK * NEXP];

    // top-1 (lower index wins ties, like lax.top_k)
    float m1 = v; int i1 = lane;
    #pragma unroll
    for (int s = 32; s > 0; s >>= 1) {
        float om = __shfl_xor(m1, s, 64);
        int   oi = __shfl_xor(i1, s, 64);
        if (om > m1 || (om == m1 && oi < i1)) { m1 = om; i1 = oi; }
    }
    // top-2: exclude i1
    float vx = (lane == i1) ? -INFINITY : v;
    float m2 = vx; int i2 = lane;
    #pragma unroll
    for (int s = 32; s > 0; s >>= 1) {
        float om = __shfl_xor(m2, s, 64);
        int   oi = __shfl_xor(i2, s, 64);
        if (om > m2 || (om == m2 && oi < i2)) { m2 = om; i2 = oi; }
    }

    float e2 = expf(m2 - m1);
    float p1 = 1.f / (1.f + e2);
    float p2 = 1.f - p1;

    float prob = (lane == i1) ? p1 : ((lane == i2) ? p2 : 0.f);
    float flag = (lane == i1 || lane == i2) ? 1.f : 0.f;
    probs[(size_t)token * NEXP + lane] = prob;
    rmap [(size_t)token * NEXP + lane] = flag;
}

extern "C" void kernel_launch(void* const* d_in, const int* in_sizes, int n_in,
                              void* d_out, int out_size, void* d_ws, size_t ws_size,
                              hipStream_t stream) {
    const float* X = (const float*)d_in[0];   // [8192,4096]
    const float* W = (const float*)d_in[1];   // [64,4096]
    float* out  = (float*)d_out;
    float* part = (float*)d_ws;               // [8][8192][64] floats = 16MB

    logits_kernel<<<128 * HG, 64, 0, stream>>>(X, W, part);
    topk_kernel<<<NTOK / 4, 256, 0, stream>>>(part, out, out + (size_t)NTOK * NEXP);
}